// Round 1
// baseline (22247.325 us; speedup 1.0000x reference)
//
#include <hip/hip_runtime.h>

// Sizes fixed by the reference.
namespace {
constexpr int E_ = 512;
constexpr int H_ = 512;
constexpr int O_ = 32;
constexpr int B_ = 64;
constexpr int T_ = 512;
}

__device__ __forceinline__ float dot4(float4 a, float4 b) {
    return fmaf(a.x, b.x, fmaf(a.y, b.y, fmaf(a.z, b.z, a.w * b.w)));
}

__device__ __forceinline__ float wave_reduce(float acc) {
#pragma unroll
    for (int off = 32; off > 0; off >>= 1)
        acc += __shfl_down(acc, off, 64);
    return acc;
}

__global__ __launch_bounds__(1024, 1) void rnn_fused(
    const int* __restrict__ x,          // [B,T] (harness delivers integer inputs as int32)
    const int* __restrict__ seq_lens,   // [B]
    const float* __restrict__ emb,      // [V,E]
    const float* __restrict__ Whx,      // [L,H,E]
    const float* __restrict__ Whh,      // [L,H,H]
    const float* __restrict__ b_h,      // [L,H]
    const float* __restrict__ Wyh,      // [L,H,H]
    const float* __restrict__ b_y,      // [L,H]
    const float* __restrict__ Wf,       // [O,H]
    const float* __restrict__ bf,       // [O]
    float* __restrict__ out)            // [B,O]
{
    const int b    = blockIdx.x;
    const int tid  = threadIdx.x;
    const int wave = tid >> 6;     // 16 waves
    const int lane = tid & 63;
    const int k0   = lane << 3;    // 8 floats of K per lane

    __shared__ float s_inp[E_];
    __shared__ float s_h0[2][H_];
    __shared__ float s_h1[2][H_];
    __shared__ float s_y[H_];

    if (tid < H_) {
        s_h0[0][tid] = 0.f; s_h0[1][tid] = 0.f;
        s_h1[0][tid] = 0.f; s_h1[1][tid] = 0.f;
    }

    const int Tb = seq_lens[b];
    const float* __restrict__ Whx0 = Whx;
    const float* __restrict__ Whx1 = Whx + H_ * E_;
    const float* __restrict__ Whh0 = Whh;
    const float* __restrict__ Whh1 = Whh + H_ * H_;

    for (int t = 0; t < Tb; ++t) {
        const int cur = t & 1, prv = cur ^ 1;

        // stage embedding row for this token
        if (tid < E_) {
            const int tok = x[b * T_ + t];
            s_inp[tid] = emb[(size_t)tok * E_ + tid];
        }
        __syncthreads();

        // per-lane input slices (reused for all 32 rows this wave owns)
        const float4 iA = *(const float4*)&s_inp[k0];
        const float4 iB = *(const float4*)&s_inp[k0 + 4];
        const float4 pA = *(const float4*)&s_h0[prv][k0];
        const float4 pB = *(const float4*)&s_h0[prv][k0 + 4];

        // layer 0: h0 = tanh(Whx0 @ inp + Whh0 @ h0_prev + b0)
#pragma unroll 4
        for (int r = 0; r < 32; ++r) {
            const int i = (wave << 5) + r;
            const float4 wa = *(const float4*)&Whx0[i * E_ + k0];
            const float4 wb = *(const float4*)&Whx0[i * E_ + k0 + 4];
            const float4 wc = *(const float4*)&Whh0[i * H_ + k0];
            const float4 wd = *(const float4*)&Whh0[i * H_ + k0 + 4];
            float acc = dot4(wa, iA) + dot4(wb, iB) + dot4(wc, pA) + dot4(wd, pB);
            acc = wave_reduce(acc);
            if (lane == 0) s_h0[cur][i] = tanhf(acc + b_h[i]);
        }
        __syncthreads();

        const float4 cA = *(const float4*)&s_h0[cur][k0];
        const float4 cB = *(const float4*)&s_h0[cur][k0 + 4];
        const float4 qA = *(const float4*)&s_h1[prv][k0];
        const float4 qB = *(const float4*)&s_h1[prv][k0 + 4];

        // layer 1: h1 = tanh(Whx1 @ h0 + Whh1 @ h1_prev + b1)
#pragma unroll 4
        for (int r = 0; r < 32; ++r) {
            const int i = (wave << 5) + r;
            const float4 wa = *(const float4*)&Whx1[i * E_ + k0];
            const float4 wb = *(const float4*)&Whx1[i * E_ + k0 + 4];
            const float4 wc = *(const float4*)&Whh1[i * H_ + k0];
            const float4 wd = *(const float4*)&Whh1[i * H_ + k0 + 4];
            float acc = dot4(wa, cA) + dot4(wb, cB) + dot4(wc, qA) + dot4(wd, qB);
            acc = wave_reduce(acc);
            if (lane == 0) s_h1[cur][i] = tanhf(acc + b_h[H_ + i]);
        }
        __syncthreads();
    }

    // y = Wyh[1] @ h1_last + b_y[1]
    const int lastb = (Tb - 1) & 1;
    const float4 hA = *(const float4*)&s_h1[lastb][k0];
    const float4 hB = *(const float4*)&s_h1[lastb][k0 + 4];
    const float* __restrict__ Wy1 = Wyh + H_ * H_;
#pragma unroll 4
    for (int r = 0; r < 32; ++r) {
        const int i = (wave << 5) + r;
        const float4 wa = *(const float4*)&Wy1[i * H_ + k0];
        const float4 wb = *(const float4*)&Wy1[i * H_ + k0 + 4];
        float acc = dot4(wa, hA) + dot4(wb, hB);
        acc = wave_reduce(acc);
        if (lane == 0) s_y[i] = acc + b_y[H_ + i];
    }
    __syncthreads();

    // out = Wf @ y + bf  (32 outputs; waves 0..7 compute 4 each)
    const float4 yA = *(const float4*)&s_y[k0];
    const float4 yB = *(const float4*)&s_y[k0 + 4];
    if (wave < 8) {
#pragma unroll
        for (int r = 0; r < 4; ++r) {
            const int o = (wave << 2) + r;
            const float4 wa = *(const float4*)&Wf[o * H_ + k0];
            const float4 wb = *(const float4*)&Wf[o * H_ + k0 + 4];
            float acc = dot4(wa, yA) + dot4(wb, yB);
            acc = wave_reduce(acc);
            if (lane == 0) out[b * O_ + o] = acc + bf[o];
        }
    }
}

extern "C" void kernel_launch(void* const* d_in, const int* in_sizes, int n_in,
                              void* d_out, int out_size, void* d_ws, size_t ws_size,
                              hipStream_t stream) {
    const int*   x    = (const int*)d_in[0];
    const int*   sl   = (const int*)d_in[1];
    const float* emb  = (const float*)d_in[2];
    const float* Whx  = (const float*)d_in[3];
    const float* Whh  = (const float*)d_in[4];
    const float* b_h  = (const float*)d_in[5];
    const float* Wyh  = (const float*)d_in[6];
    const float* b_y  = (const float*)d_in[7];
    const float* Wf   = (const float*)d_in[8];
    const float* bf   = (const float*)d_in[9];
    float* out = (float*)d_out;

    rnn_fused<<<B_, 1024, 0, stream>>>(x, sl, emb, Whx, Whh, b_h, Wyh, b_y, Wf, bf, out);
}

// Round 2
// 5615.893 us; speedup vs baseline: 3.9615x; 3.9615x over previous
//
#include <hip/hip_runtime.h>

namespace {
constexpr int E_ = 512;
constexpr int H_ = 512;
constexpr int O_ = 32;
constexpr int B_ = 64;
constexpr int T_ = 512;
constexpr int RING = 8;     // h ring depth (slots)
// ws layout (in floats)
constexpr size_t H0_OFF  = 0;                       // RING*B*H = 262144 floats
constexpr size_t H1_OFF  = 262144;                  // 262144 floats
constexpr size_t HF_OFF  = 524288;                  // B*H = 32768 floats
constexpr size_t CNT_OFF = 557056;                  // 2 * 8*512*8 uints
constexpr size_t CNT_UINTS_PER = 8u * 512u * 8u;    // 32768
constexpr size_t WS_REQUIRED = (CNT_OFF + 2 * CNT_UINTS_PER) * 4; // 2,490,368 B
}

typedef float f32x4 __attribute__((ext_vector_type(4)));

// ---- coherent (device-scope, LLC) loads/stores: bypass non-coherent L1/L2 ----
__device__ __forceinline__ void coh_load2(const float* p, f32x4& a, f32x4& b) {
    asm volatile(
        "global_load_dwordx4 %0, %2, off sc0 sc1\n\t"
        "global_load_dwordx4 %1, %3, off sc0 sc1\n\t"
        "s_waitcnt vmcnt(0)"
        : "=&v"(a), "=&v"(b)
        : "v"(p), "v"(p + 4)
        : "memory");
}

__device__ __forceinline__ void coh_load4(const float* p, const float* q,
                                          f32x4& a, f32x4& b, f32x4& c, f32x4& d) {
    asm volatile(
        "global_load_dwordx4 %0, %4, off sc0 sc1\n\t"
        "global_load_dwordx4 %1, %5, off sc0 sc1\n\t"
        "global_load_dwordx4 %2, %6, off sc0 sc1\n\t"
        "global_load_dwordx4 %3, %7, off sc0 sc1\n\t"
        "s_waitcnt vmcnt(0)"
        : "=&v"(a), "=&v"(b), "=&v"(c), "=&v"(d)
        : "v"(p), "v"(p + 4), "v"(q), "v"(q + 4)
        : "memory");
}

__device__ __forceinline__ void coh_store(float* p, float v) {
    asm volatile("global_store_dword %0, %1, off sc0 sc1" :: "v"(p), "v"(v) : "memory");
}

// =====================================================================
// Pipelined RNN: 256 blocks = 2 layers x 8 batch-groups x 16 row-chunks.
// Each block: 8 batch elems x 32 rows. Weights live in registers
// (lane k-slice of 16 over K=1024 = [Wx row | Wh row]), activations staged
// in LDS per step. h exchanged via ring buffers + per-(g,t) flag counters.
// =====================================================================
__global__ __launch_bounds__(512, 2) void rnn_pipe(
    const int* __restrict__ x, const int* __restrict__ seq_lens,
    const float* __restrict__ emb,
    const float* __restrict__ Whx, const float* __restrict__ Whh,
    const float* __restrict__ b_h,
    float* __restrict__ h0_ring, float* __restrict__ h1_ring,
    float* __restrict__ h1_final,
    unsigned int* cnt0, unsigned int* cnt1)
{
    const int bid   = blockIdx.x;
    const int layer = bid >> 7;          // 0..1
    const int g     = (bid >> 4) & 7;    // batch group 0..7 (8 elems each)
    const int c     = bid & 15;          // row chunk 0..15 (32 rows each)
    const int tid   = threadIdx.x;
    const int wid   = tid >> 6;          // 8 waves
    const int lane  = tid & 63;
    const int wr    = wid & 3;           // row sub-chunk (8 rows)
    const int we    = wid >> 2;          // elem half (4 elems)
    const int row0  = c * 32 + wr * 8;

    // LDS: L0: [0..4096) x-buf0, [4096..8192) x-buf1, [8192..12288) h0_prev
    //      L1: [0..4096) h0(t),  [4096..8192) h1_prev
    __shared__ float smem[12288];

    // ---- persistent per-lane weights: w[r][j], k = lane*16 + j over K=1024 ----
    const float* WxL = Whx + (size_t)layer * H_ * E_;
    const float* WhL = Whh + (size_t)layer * H_ * H_;
    const float* wbase = (lane < 32) ? (WxL + lane * 16) : (WhL + (lane - 32) * 16);
    float w[8][16];
#pragma unroll
    for (int r = 0; r < 8; ++r) {
        const f32x4* p = (const f32x4*)(wbase + (size_t)(row0 + r) * 512);
#pragma unroll
        for (int j = 0; j < 4; ++j) {
            f32x4 v = p[j];
            w[r][j * 4 + 0] = v[0]; w[r][j * 4 + 1] = v[1];
            w[r][j * 4 + 2] = v[2]; w[r][j * 4 + 3] = v[3];
        }
    }
    float bias[8];
#pragma unroll
    for (int r = 0; r < 8; ++r) bias[r] = b_h[layer * H_ + row0 + r];

    int sl4[4];
#pragma unroll
    for (int q = 0; q < 4; ++q) sl4[q] = seq_lens[(g << 3) + (we << 2) + q];

    // staging thread map
    const int se  = tid >> 6;            // elem 0..7
    const int off = (tid & 63) << 3;     // 8-float slice of 512
    const int seg = (g << 3) + se;       // global elem

    // pre-stage emb for t=0 into x-buf0
    if (layer == 0) {
        const int tok = x[(size_t)seg * T_];
        const f32x4* er = (const f32x4*)(emb + ((size_t)tok << 9) + off);
        f32x4* dx = (f32x4*)(smem + (se << 9) + off);
        dx[0] = er[0]; dx[1] = er[1];
    }
    __syncthreads();

    float* const oring = (layer == 0) ? h0_ring : h1_ring;
    int64_t spin_budget = 1ll << 26;
    auto spin16 = [&](unsigned int* f) {
        while (__hip_atomic_load(f, __ATOMIC_RELAXED, __HIP_MEMORY_SCOPE_AGENT) < 16u) {
            if (--spin_budget < 0) break;
            __builtin_amdgcn_s_sleep(1);
        }
    };

    for (int t = 0; t < T_; ++t) {
        const int slot  = t & (RING - 1);
        const int pslot = (t - 1) & (RING - 1);

        // ---- wait for dependencies ----
        if (tid == 0) {
            if (layer == 0) {
                if (t >= 1)    spin16(cnt0 + ((((unsigned)g << 9) + (t - 1)) << 3));
                if (t >= RING) spin16(cnt1 + ((((unsigned)g << 9) + (t - RING)) << 3)); // ring backpressure
            } else {
                spin16(cnt0 + ((((unsigned)g << 9) + t) << 3));
                if (t >= 1)    spin16(cnt1 + ((((unsigned)g << 9) + (t - 1)) << 3));
            }
        }
        __syncthreads();

        // ---- stage activations into LDS (coherent loads from rings) ----
        if (layer == 0) {
            float* hp = smem + 8192 + (se << 9) + off;
            if (t == 0) {
                f32x4 z = 0; ((f32x4*)hp)[0] = z; ((f32x4*)hp)[1] = z;
            } else {
                const float* s = h0_ring + (((size_t)pslot << 6) + seg) * 512 + off;
                f32x4 a, b2; coh_load2(s, a, b2);
                ((f32x4*)hp)[0] = a; ((f32x4*)hp)[1] = b2;
            }
        } else {
            float* si = smem + (se << 9) + off;
            float* hp = smem + 4096 + (se << 9) + off;
            const float* s0 = h0_ring + (((size_t)slot << 6) + seg) * 512 + off;
            if (t == 0) {
                f32x4 a, b2; coh_load2(s0, a, b2);
                ((f32x4*)si)[0] = a; ((f32x4*)si)[1] = b2;
                f32x4 z = 0; ((f32x4*)hp)[0] = z; ((f32x4*)hp)[1] = z;
            } else {
                const float* s1 = h1_ring + (((size_t)pslot << 6) + seg) * 512 + off;
                f32x4 a, b2, c2, d2; coh_load4(s0, s1, a, b2, c2, d2);
                ((f32x4*)si)[0] = a; ((f32x4*)si)[1] = b2;
                ((f32x4*)hp)[0] = c2; ((f32x4*)hp)[1] = d2;
            }
        }
        __syncthreads();

        // ---- issue emb prefetch for t+1 (plain loads; land during compute) ----
        f32x4 pf0, pf1;
        const bool havepf = (layer == 0) && (t + 1 < T_);
        if (havepf) {
            const int tok = x[(size_t)seg * T_ + t + 1];
            const f32x4* er = (const f32x4*)(emb + ((size_t)tok << 9) + off);
            pf0 = er[0]; pf1 = er[1];
        }

        // ---- compute: 4 elems x 8 rows per wave ----
        const float* alo_base = (layer == 0) ? (smem + ((t & 1) << 12)) : smem;
        const float* ahi_base = (layer == 0) ? (smem + 8192) : (smem + 4096);
#pragma unroll
        for (int q = 0; q < 4; ++q) {
            const int slq = sl4[q];
            if (t >= slq) continue;                       // elem finished (uniform per wave)
            const int el  = (we << 2) + q;
            const int egq = (g << 3) + el;
            const float* ap = (lane < 32)
                ? (alo_base + (el << 9) + (lane << 4))
                : (ahi_base + (el << 9) + ((lane - 32) << 4));
            f32x4 A[4];
            const f32x4* ap4 = (const f32x4*)ap;
            A[0] = ap4[0]; A[1] = ap4[1]; A[2] = ap4[2]; A[3] = ap4[3];

            float red[8];
#pragma unroll
            for (int r = 0; r < 8; ++r) {
                float s = w[r][0] * A[0][0];
#pragma unroll
                for (int j = 1; j < 16; ++j)
                    s = fmaf(w[r][j], A[j >> 2][j & 3], s);
                red[r] = s;
            }
#pragma unroll
            for (int r = 0; r < 8; ++r) {
                float v = red[r];
                v += __shfl_down(v, 32);
                v += __shfl_down(v, 16);
                v += __shfl_down(v, 8);
                v += __shfl_down(v, 4);
                v += __shfl_down(v, 2);
                v += __shfl_down(v, 1);
                if (lane == 0) {
                    const float hv = tanhf(v + bias[r]);
                    coh_store(oring + (((size_t)slot << 6) + egq) * 512 + row0 + r, hv);
                    if (layer == 1 && t == slq - 1)
                        h1_final[(size_t)egq * 512 + row0 + r] = hv;   // plain; next kernel
                }
            }
        }

        // ---- write prefetched emb into the other x-buffer ----
        if (havepf) {
            f32x4* dx = (f32x4*)(smem + (((t + 1) & 1) << 12) + (se << 9) + off);
            dx[0] = pf0; dx[1] = pf1;
        }

        // ---- publish: all stores drained per-wave by barrier, then flag ----
        __syncthreads();
        if (tid == 0) {
            unsigned int* f = (layer == 0 ? cnt0 : cnt1) + ((((unsigned)g << 9) + t) << 3);
            __hip_atomic_fetch_add(f, 1u, __ATOMIC_RELEASE, __HIP_MEMORY_SCOPE_AGENT);
        }
    }
}

// ---- final head: y = Wyh[1] @ h1_final + b_y[1]; out = Wf @ y + bf ----
__device__ __forceinline__ float dot4(float4 a, float4 b) {
    return fmaf(a.x, b.x, fmaf(a.y, b.y, fmaf(a.z, b.z, a.w * b.w)));
}
__device__ __forceinline__ float wave_reduce(float acc) {
#pragma unroll
    for (int off = 32; off > 0; off >>= 1) acc += __shfl_down(acc, off, 64);
    return acc;
}

__global__ __launch_bounds__(512) void head_kernel(
    const float* __restrict__ h1f, const float* __restrict__ Wyh,
    const float* __restrict__ b_y, const float* __restrict__ Wf,
    const float* __restrict__ bf, float* __restrict__ out)
{
    const int e = blockIdx.x;
    const int tid = threadIdx.x, wid = tid >> 6, lane = tid & 63;
    const int k0 = lane << 3;
    __shared__ float sh[H_];
    __shared__ float sy[H_];
    sh[tid] = h1f[(size_t)e * H_ + tid];
    __syncthreads();
    const float4 hA = *(const float4*)&sh[k0];
    const float4 hB = *(const float4*)&sh[k0 + 4];
    const float* Wy1 = Wyh + H_ * H_;
#pragma unroll 4
    for (int rr = 0; rr < 64; ++rr) {
        const int row = (wid << 6) + rr;
        const float4 wa = *(const float4*)&Wy1[(size_t)row * H_ + k0];
        const float4 wb = *(const float4*)&Wy1[(size_t)row * H_ + k0 + 4];
        float acc = wave_reduce(dot4(wa, hA) + dot4(wb, hB));
        if (lane == 0) sy[row] = acc + b_y[H_ + row];
    }
    __syncthreads();
    const float4 yA = *(const float4*)&sy[k0];
    const float4 yB = *(const float4*)&sy[k0 + 4];
#pragma unroll
    for (int rr = 0; rr < 4; ++rr) {
        const int o = (wid << 2) + rr;
        const float4 wa = *(const float4*)&Wf[(size_t)o * H_ + k0];
        const float4 wb = *(const float4*)&Wf[(size_t)o * H_ + k0 + 4];
        float acc = wave_reduce(dot4(wa, yA) + dot4(wb, yB));
        if (lane == 0) out[(size_t)e * O_ + o] = acc + bf[o];
    }
}

// =====================================================================
// Fallback (round-0 kernel, known-passing) in case ws is too small.
// =====================================================================
__global__ __launch_bounds__(1024, 1) void rnn_fused_fb(
    const int* __restrict__ x, const int* __restrict__ seq_lens,
    const float* __restrict__ emb, const float* __restrict__ Whx,
    const float* __restrict__ Whh, const float* __restrict__ b_h,
    const float* __restrict__ Wyh, const float* __restrict__ b_y,
    const float* __restrict__ Wf, const float* __restrict__ bf,
    float* __restrict__ out)
{
    const int b = blockIdx.x, tid = threadIdx.x;
    const int wave = tid >> 6, lane = tid & 63, k0 = lane << 3;
    __shared__ float s_inp[E_];
    __shared__ float s_h0[2][H_];
    __shared__ float s_h1[2][H_];
    __shared__ float s_y[H_];
    if (tid < H_) { s_h0[0][tid]=0.f; s_h0[1][tid]=0.f; s_h1[0][tid]=0.f; s_h1[1][tid]=0.f; }
    const int Tb = seq_lens[b];
    const float* Whx0 = Whx; const float* Whx1 = Whx + H_*E_;
    const float* Whh0 = Whh; const float* Whh1 = Whh + H_*H_;
    for (int t = 0; t < Tb; ++t) {
        const int cur = t & 1, prv = cur ^ 1;
        if (tid < E_) { const int tok = x[b*T_+t]; s_inp[tid] = emb[(size_t)tok*E_+tid]; }
        __syncthreads();
        const float4 iA = *(const float4*)&s_inp[k0], iB = *(const float4*)&s_inp[k0+4];
        const float4 pA = *(const float4*)&s_h0[prv][k0], pB = *(const float4*)&s_h0[prv][k0+4];
#pragma unroll 4
        for (int r = 0; r < 32; ++r) {
            const int i = (wave<<5)+r;
            float acc = dot4(*(const float4*)&Whx0[i*E_+k0], iA) + dot4(*(const float4*)&Whx0[i*E_+k0+4], iB)
                      + dot4(*(const float4*)&Whh0[i*H_+k0], pA) + dot4(*(const float4*)&Whh0[i*H_+k0+4], pB);
            acc = wave_reduce(acc);
            if (lane == 0) s_h0[cur][i] = tanhf(acc + b_h[i]);
        }
        __syncthreads();
        const float4 cA = *(const float4*)&s_h0[cur][k0], cB = *(const float4*)&s_h0[cur][k0+4];
        const float4 qA = *(const float4*)&s_h1[prv][k0], qB = *(const float4*)&s_h1[prv][k0+4];
#pragma unroll 4
        for (int r = 0; r < 32; ++r) {
            const int i = (wave<<5)+r;
            float acc = dot4(*(const float4*)&Whx1[i*E_+k0], cA) + dot4(*(const float4*)&Whx1[i*E_+k0+4], cB)
                      + dot4(*(const float4*)&Whh1[i*H_+k0], qA) + dot4(*(const float4*)&Whh1[i*H_+k0+4], qB);
            acc = wave_reduce(acc);
            if (lane == 0) s_h1[cur][i] = tanhf(acc + b_h[H_+i]);
        }
        __syncthreads();
    }
    const int lastb = (Tb-1) & 1;
    const float4 hA = *(const float4*)&s_h1[lastb][k0], hB = *(const float4*)&s_h1[lastb][k0+4];
    const float* Wy1 = Wyh + H_*H_;
#pragma unroll 4
    for (int r = 0; r < 32; ++r) {
        const int i = (wave<<5)+r;
        float acc = wave_reduce(dot4(*(const float4*)&Wy1[i*H_+k0], hA) + dot4(*(const float4*)&Wy1[i*H_+k0+4], hB));
        if (lane == 0) s_y[i] = acc + b_y[H_+i];
    }
    __syncthreads();
    const float4 yA = *(const float4*)&s_y[k0], yB = *(const float4*)&s_y[k0+4];
    if (wave < 8) {
#pragma unroll
        for (int r = 0; r < 4; ++r) {
            const int o = (wave<<2)+r;
            float acc = wave_reduce(dot4(*(const float4*)&Wf[o*H_+k0], yA) + dot4(*(const float4*)&Wf[o*H_+k0+4], yB));
            if (lane == 0) out[b*O_+o] = acc + bf[o];
        }
    }
}

extern "C" void kernel_launch(void* const* d_in, const int* in_sizes, int n_in,
                              void* d_out, int out_size, void* d_ws, size_t ws_size,
                              hipStream_t stream) {
    const int*   x    = (const int*)d_in[0];
    const int*   sl   = (const int*)d_in[1];
    const float* emb  = (const float*)d_in[2];
    const float* Whx  = (const float*)d_in[3];
    const float* Whh  = (const float*)d_in[4];
    const float* b_h  = (const float*)d_in[5];
    const float* Wyh  = (const float*)d_in[6];
    const float* b_y  = (const float*)d_in[7];
    const float* Wf   = (const float*)d_in[8];
    const float* bf   = (const float*)d_in[9];
    float* out = (float*)d_out;

    if (ws_size < WS_REQUIRED) {
        rnn_fused_fb<<<B_, 1024, 0, stream>>>(x, sl, emb, Whx, Whh, b_h, Wyh, b_y, Wf, bf, out);
        return;
    }

    float* ws_f = (float*)d_ws;
    float* h0_ring = ws_f + H0_OFF;
    float* h1_ring = ws_f + H1_OFF;
    float* h1f     = ws_f + HF_OFF;
    unsigned int* cnt0 = (unsigned int*)(ws_f + CNT_OFF);
    unsigned int* cnt1 = cnt0 + CNT_UINTS_PER;

    hipMemsetAsync(cnt0, 0, 2 * CNT_UINTS_PER * sizeof(unsigned int), stream);
    rnn_pipe<<<256, 512, 0, stream>>>(x, sl, emb, Whx, Whh, b_h,
                                      h0_ring, h1_ring, h1f, cnt0, cnt1);
    head_kernel<<<B_, 512, 0, stream>>>(h1f, Wyh, b_y, Wf, bf, out);
}

// Round 3
// 2207.383 us; speedup vs baseline: 10.0786x; 2.5441x over previous
//
#include <hip/hip_runtime.h>

namespace {
constexpr int E_ = 512;
constexpr int H_ = 512;
constexpr int O_ = 32;
constexpr int B_ = 64;
constexpr int T_ = 512;
constexpr int RING = 8;
constexpr int FPAD = 16; // uints per flag slot (64B line)
// ws layout (floats)
constexpr size_t H0_OFF   = 0;                                  // RING*B*H
constexpr size_t H1_OFF   = (size_t)RING * B_ * H_;             // 262144
constexpr size_t HF_OFF   = 2 * H1_OFF;                         // 524288
constexpr size_t FLAG_OFF = HF_OFF + (size_t)B_ * H_;           // 557056 (floats)
constexpr size_t FLAG_UINTS = 2u * 8u * 16u * FPAD;             // 4096
constexpr size_t WS_REQUIRED = (FLAG_OFF + FLAG_UINTS) * 4;
}

typedef float f32x4 __attribute__((ext_vector_type(4)));

// ---- coherent LLC ops (bypass non-coherent L1/L2) ----
__device__ __forceinline__ void ring_issue4(const float* p, f32x4& a, f32x4& b,
                                            f32x4& c, f32x4& d) {
    // 4x dwordx4 at +0,+1024,+2048,+3072 bytes: two elems x two k-chunks. No wait.
    asm volatile(
        "global_load_dwordx4 %0, %4, off sc0 sc1\n\t"
        "global_load_dwordx4 %1, %4, off offset:1024 sc0 sc1\n\t"
        "global_load_dwordx4 %2, %4, off offset:2048 sc0 sc1\n\t"
        "global_load_dwordx4 %3, %4, off offset:3072 sc0 sc1"
        : "=&v"(a), "=&v"(b), "=&v"(c), "=&v"(d)
        : "v"(p) : "memory");
}
__device__ __forceinline__ void vm_drain() {
    asm volatile("s_waitcnt vmcnt(0)" ::: "memory");
}
__device__ __forceinline__ void coh_store(float* p, float v) {
    asm volatile("global_store_dword %0, %1, off sc0 sc1" :: "v"(p), "v"(v) : "memory");
}
__device__ __forceinline__ void flag_store(unsigned* p, unsigned v) {
    asm volatile("global_store_dword %0, %1, off sc0 sc1" :: "v"(p), "v"(v) : "memory");
}
__device__ __forceinline__ unsigned flag_load(const unsigned* p) {
    unsigned v;
    asm volatile("global_load_dword %0, %1, off sc0 sc1\n\ts_waitcnt vmcnt(0)"
                 : "=&v"(v) : "v"(p) : "memory");
    return v;
}

__device__ __forceinline__ float fast_tanh(float x) {
    // tanh(x) = 1 - 2/(exp2(2*log2e*x)+1); monotone-safe at +-inf
    float e = __builtin_amdgcn_exp2f(x * 2.885390081777927f);
    return 1.0f - 2.0f * __builtin_amdgcn_rcpf(e + 1.0f);
}

// pair-combine butterfly: in: v[8] partials per lane; out: full sum of row (lane&7)
__device__ __forceinline__ float reduce8(const float v[8], int lane) {
    float a[4];
#pragma unroll
    for (int j = 0; j < 4; ++j) {
        const int sel = lane & 1;
        const float mine = sel ? v[2 * j + 1] : v[2 * j];
        const float send = sel ? v[2 * j] : v[2 * j + 1];
        a[j] = mine + __shfl_xor(send, 1, 64);
    }
    float b[2];
#pragma unroll
    for (int j = 0; j < 2; ++j) {
        const int sel = (lane >> 1) & 1;
        const float mine = sel ? a[2 * j + 1] : a[2 * j];
        const float send = sel ? a[2 * j] : a[2 * j + 1];
        b[j] = mine + __shfl_xor(send, 2, 64);
    }
    const int sel = (lane >> 2) & 1;
    const float mine = sel ? b[1] : b[0];
    const float send = sel ? b[0] : b[1];
    float s = mine + __shfl_xor(send, 4, 64);
    s += __shfl_xor(s, 8, 64);
    s += __shfl_xor(s, 16, 64);
    s += __shfl_xor(s, 32, 64);
    return s;
}

// =====================================================================
// 256 blocks = 2 layers x 8 groups x 16 row-chunks; 512 thr = 8 waves.
// Wave: rows [c*32 + (wid&3)*8, +8) x elems [(wid>>2)*4, +4).
// Lane k-slice (row dot): k = chunk*256 + lane*4 + m  (x-part chunks 0,1;
// h-part same) -> all LDS/global accesses lane-contiguous 16B.
// =====================================================================
__global__ __launch_bounds__(512, 2) void rnn_pipe2(
    const int* __restrict__ x, const int* __restrict__ seq_lens,
    const float* __restrict__ emb,
    const float* __restrict__ Whx, const float* __restrict__ Whh,
    const float* __restrict__ b_h,
    float* __restrict__ h0_ring, float* __restrict__ h1_ring,
    float* __restrict__ h1_final, unsigned* __restrict__ flags)
{
    const int bid   = blockIdx.x;
    const int layer = bid >> 7;
    const int g     = (bid >> 4) & 7;
    const int c     = bid & 15;
    const int tid   = threadIdx.x;
    const int wid   = tid >> 6;
    const int lane  = tid & 63;
    const int wr    = wid & 3;
    const int we    = wid >> 2;
    const int rowbase = c * 32 + wr * 8;

    __shared__ float sx[2][4096];   // emb double-buffer (layer 0 only)

    // ---- persistent weights: w[r][0..7]=x-part, [8..15]=h-part ----
    const float* WxL = Whx + (size_t)layer * H_ * E_;
    const float* WhL = Whh + (size_t)layer * H_ * H_;
    float w[8][16];
#pragma unroll
    for (int r = 0; r < 8; ++r) {
        const int row = rowbase + r;
        const f32x4 x0 = *(const f32x4*)(WxL + (size_t)row * E_ + (lane << 2));
        const f32x4 x1 = *(const f32x4*)(WxL + (size_t)row * E_ + 256 + (lane << 2));
        const f32x4 h0 = *(const f32x4*)(WhL + (size_t)row * H_ + (lane << 2));
        const f32x4 h1 = *(const f32x4*)(WhL + (size_t)row * H_ + 256 + (lane << 2));
#pragma unroll
        for (int m = 0; m < 4; ++m) {
            w[r][m] = x0[m]; w[r][4 + m] = x1[m];
            w[r][8 + m] = h0[m]; w[r][12 + m] = h1[m];
        }
    }
    const float bias = b_h[layer * H_ + rowbase + (lane & 7)];

    int sl4[4];
#pragma unroll
    for (int q = 0; q < 4; ++q) sl4[q] = seq_lens[(g << 3) + (we << 2) + q];
    int Tg = 1;
#pragma unroll
    for (int j = 0; j < 8; ++j) {
        const int s = seq_lens[(g << 3) + j];
        Tg = s > Tg ? s : Tg;
    }

    // flags: set0/set1 each [8][16] x FPAD
    unsigned* const f0 = flags;
    unsigned* const f1 = flags + 128 * FPAD;
    unsigned* const myflag = (layer == 0 ? f0 : f1) + ((g << 4) + c) * FPAD;
    const unsigned* pollp = f0;
    int which = 0;
    if (wid == 0) {
        if (lane < 16)      { pollp = f0 + ((g << 4) + lane) * FPAD;        which = 1; }
        else if (lane < 32) { pollp = f1 + ((g << 4) + (lane - 16)) * FPAD; which = 2; }
    }

    // staging map for emb prefetch: se = elem, two 16B chunks per thread
    const int se  = tid >> 6;
    const int seg = (g << 3) + se;

    if (layer == 0) {
        const int tok = x[(size_t)seg * T_];
        const f32x4* er = (const f32x4*)(emb + ((size_t)tok << 9) + (lane << 2));
        *(f32x4*)&sx[0][(se << 9) + (lane << 2)]       = er[0];
        *(f32x4*)&sx[0][(se << 9) + 256 + (lane << 2)] = er[64];
    }

    const int egbase = (g << 3) + (we << 2);
    long spin_budget = 1l << 27;

    for (int t = 0; t < Tg; ++t) {
        const int slot  = t & (RING - 1);
        const int pslot = (t - 1) & (RING - 1);

        // ---- poll (wave 0, lane-parallel over both flag sets) ----
        {
            int tA, tB;
            if (layer == 0) { tA = t;     tB = t - (RING - 1); }
            else            { tA = t + 1; tB = t; }
            const unsigned uA = tA > 0 ? (unsigned)tA : 0u;
            const unsigned uB = tB > 0 ? (unsigned)tB : 0u;
            if (wid == 0 && (uA | uB)) {
                for (;;) {
                    const unsigned fv = flag_load(pollp);
                    const bool bad = (which == 1 && fv < uA) || (which == 2 && fv < uB);
                    if (!__any(bad)) break;
                    if (--spin_budget < 0) break;
                    __builtin_amdgcn_s_sleep(1);
                }
            }
        }
        __syncthreads();

        // ---- issue h loads (global -> reg, coherent) ----
        f32x4 xr[4][2], hr[4][2];
        if (layer == 1) {
            const float* px = h0_ring + (((size_t)slot << 6) + egbase) * 512 + (lane << 2);
            ring_issue4(px,        xr[0][0], xr[0][1], xr[1][0], xr[1][1]);
            ring_issue4(px + 1024, xr[2][0], xr[2][1], xr[3][0], xr[3][1]);
            if (t > 0) {
                const float* ph = h1_ring + (((size_t)pslot << 6) + egbase) * 512 + (lane << 2);
                ring_issue4(ph,        hr[0][0], hr[0][1], hr[1][0], hr[1][1]);
                ring_issue4(ph + 1024, hr[2][0], hr[2][1], hr[3][0], hr[3][1]);
            } else {
#pragma unroll
                for (int q = 0; q < 4; ++q) { hr[q][0] = 0; hr[q][1] = 0; }
            }
        } else {
            if (t > 0) {
                const float* ph = h0_ring + (((size_t)pslot << 6) + egbase) * 512 + (lane << 2);
                ring_issue4(ph,        hr[0][0], hr[0][1], hr[1][0], hr[1][1]);
                ring_issue4(ph + 1024, hr[2][0], hr[2][1], hr[3][0], hr[3][1]);
            } else {
#pragma unroll
                for (int q = 0; q < 4; ++q) { hr[q][0] = 0; hr[q][1] = 0; }
            }
        }
        vm_drain();
        __builtin_amdgcn_sched_barrier(0);

        // ---- emb prefetch for t+1 (plain cached loads; land during compute) ----
        f32x4 pf0, pf1;
        const bool havepf = (layer == 0) && (t + 1 < Tg);
        if (havepf) {
            const int tok = x[(size_t)seg * T_ + t + 1];
            const f32x4* er = (const f32x4*)(emb + ((size_t)tok << 9) + (lane << 2));
            pf0 = er[0]; pf1 = er[64];
        }

        // ---- compute: 4 elems x 8 rows per wave ----
        float* const oring = (layer == 0) ? h0_ring : h1_ring;
#pragma unroll
        for (int q = 0; q < 4; ++q) {
            const int slq = sl4[q];
            if (t >= slq) continue;                 // wave-uniform
            const int el = (we << 2) + q;
            const int eg = egbase + q;

            float A[16];
            if (layer == 0) {
                const f32x4 lx0 = *(const f32x4*)&sx[t & 1][(el << 9) + (lane << 2)];
                const f32x4 lx1 = *(const f32x4*)&sx[t & 1][(el << 9) + 256 + (lane << 2)];
#pragma unroll
                for (int m = 0; m < 4; ++m) { A[m] = lx0[m]; A[4 + m] = lx1[m]; }
            } else {
#pragma unroll
                for (int m = 0; m < 4; ++m) { A[m] = xr[q][0][m]; A[4 + m] = xr[q][1][m]; }
            }
#pragma unroll
            for (int m = 0; m < 4; ++m) { A[8 + m] = hr[q][0][m]; A[12 + m] = hr[q][1][m]; }

            float vv[8];
#pragma unroll
            for (int r = 0; r < 8; ++r) {
                float s = w[r][0] * A[0];
#pragma unroll
                for (int j = 1; j < 16; ++j) s = fmaf(w[r][j], A[j], s);
                vv[r] = s;
            }
            const float sum = reduce8(vv, lane);
            const float hv = fast_tanh(sum + bias);
            if (lane < 8) {
                coh_store(oring + (((size_t)slot << 6) + eg) * 512 + rowbase + lane, hv);
                if (layer == 1 && t == slq - 1)
                    h1_final[((size_t)eg << 9) + rowbase + lane] = hv;
            }
        }

        // ---- write prefetched emb into other buffer ----
        if (havepf) {
            *(f32x4*)&sx[(t + 1) & 1][(se << 9) + (lane << 2)]       = pf0;
            *(f32x4*)&sx[(t + 1) & 1][(se << 9) + 256 + (lane << 2)] = pf1;
        }

        vm_drain();          // data stores ack'd at LLC
        __syncthreads();     // all waves drained
        if (tid == 0) flag_store(myflag, (unsigned)(t + 1));
    }
}

// ---- final head: y = Wyh[1] @ h1 + b_y[1]; out = Wf @ y + bf ----
__device__ __forceinline__ float dot4(float4 a, float4 b) {
    return fmaf(a.x, b.x, fmaf(a.y, b.y, fmaf(a.z, b.z, a.w * b.w)));
}
__device__ __forceinline__ float wave_reduce(float acc) {
#pragma unroll
    for (int off = 32; off > 0; off >>= 1) acc += __shfl_down(acc, off, 64);
    return acc;
}

__global__ __launch_bounds__(512) void head_kernel(
    const float* __restrict__ h1f, const float* __restrict__ Wyh,
    const float* __restrict__ b_y, const float* __restrict__ Wf,
    const float* __restrict__ bf, float* __restrict__ out)
{
    const int e = blockIdx.x;
    const int tid = threadIdx.x, wid = tid >> 6, lane = tid & 63;
    const int k0 = lane << 3;
    __shared__ float sh[H_];
    __shared__ float sy[H_];
    sh[tid] = h1f[(size_t)e * H_ + tid];
    __syncthreads();
    const float4 hA = *(const float4*)&sh[k0];
    const float4 hB = *(const float4*)&sh[k0 + 4];
    const float* Wy1 = Wyh + H_ * H_;
#pragma unroll 4
    for (int rr = 0; rr < 64; ++rr) {
        const int row = (wid << 6) + rr;
        float acc = wave_reduce(dot4(*(const float4*)&Wy1[(size_t)row * H_ + k0], hA) +
                                dot4(*(const float4*)&Wy1[(size_t)row * H_ + k0 + 4], hB));
        if (lane == 0) sy[row] = acc + b_y[H_ + row];
    }
    __syncthreads();
    const float4 yA = *(const float4*)&sy[k0];
    const float4 yB = *(const float4*)&sy[k0 + 4];
#pragma unroll
    for (int rr = 0; rr < 4; ++rr) {
        const int o = (wid << 2) + rr;
        float acc = wave_reduce(dot4(*(const float4*)&Wf[(size_t)o * H_ + k0], yA) +
                                dot4(*(const float4*)&Wf[(size_t)o * H_ + k0 + 4], yB));
        if (lane == 0) out[(size_t)e * O_ + o] = acc + bf[o];
    }
}

// ---- fallback (round-0, known-passing) ----
__global__ __launch_bounds__(1024, 1) void rnn_fused_fb(
    const int* __restrict__ x, const int* __restrict__ seq_lens,
    const float* __restrict__ emb, const float* __restrict__ Whx,
    const float* __restrict__ Whh, const float* __restrict__ b_h,
    const float* __restrict__ Wyh, const float* __restrict__ b_y,
    const float* __restrict__ Wf, const float* __restrict__ bf,
    float* __restrict__ out)
{
    const int b = blockIdx.x, tid = threadIdx.x;
    const int wave = tid >> 6, lane = tid & 63, k0 = lane << 3;
    __shared__ float s_inp[E_];
    __shared__ float s_h0[2][H_];
    __shared__ float s_h1[2][H_];
    __shared__ float s_y[H_];
    if (tid < H_) { s_h0[0][tid]=0.f; s_h0[1][tid]=0.f; s_h1[0][tid]=0.f; s_h1[1][tid]=0.f; }
    const int Tb = seq_lens[b];
    const float* Whx0 = Whx; const float* Whx1 = Whx + H_*E_;
    const float* Whh0 = Whh; const float* Whh1 = Whh + H_*H_;
    for (int t = 0; t < Tb; ++t) {
        const int cur = t & 1, prv = cur ^ 1;
        if (tid < E_) { const int tok = x[b*T_+t]; s_inp[tid] = emb[(size_t)tok*E_+tid]; }
        __syncthreads();
        const float4 iA = *(const float4*)&s_inp[k0], iB = *(const float4*)&s_inp[k0+4];
        const float4 pA = *(const float4*)&s_h0[prv][k0], pB = *(const float4*)&s_h0[prv][k0+4];
#pragma unroll 4
        for (int r = 0; r < 32; ++r) {
            const int i = (wave<<5)+r;
            float acc = dot4(*(const float4*)&Whx0[i*E_+k0], iA) + dot4(*(const float4*)&Whx0[i*E_+k0+4], iB)
                      + dot4(*(const float4*)&Whh0[i*H_+k0], pA) + dot4(*(const float4*)&Whh0[i*H_+k0+4], pB);
            acc = wave_reduce(acc);
            if (lane == 0) s_h0[cur][i] = tanhf(acc + b_h[i]);
        }
        __syncthreads();
        const float4 cA = *(const float4*)&s_h0[cur][k0], cB = *(const float4*)&s_h0[cur][k0+4];
        const float4 qA = *(const float4*)&s_h1[prv][k0], qB = *(const float4*)&s_h1[prv][k0+4];
#pragma unroll 4
        for (int r = 0; r < 32; ++r) {
            const int i = (wave<<5)+r;
            float acc = dot4(*(const float4*)&Whx1[i*E_+k0], cA) + dot4(*(const float4*)&Whx1[i*E_+k0+4], cB)
                      + dot4(*(const float4*)&Whh1[i*H_+k0], qA) + dot4(*(const float4*)&Whh1[i*H_+k0+4], qB);
            acc = wave_reduce(acc);
            if (lane == 0) s_h1[cur][i] = tanhf(acc + b_h[H_+i]);
        }
        __syncthreads();
    }
    const int lastb = (Tb-1) & 1;
    const float4 hA = *(const float4*)&s_h1[lastb][k0], hB = *(const float4*)&s_h1[lastb][k0+4];
    const float* Wy1 = Wyh + H_*H_;
#pragma unroll 4
    for (int r = 0; r < 32; ++r) {
        const int i = (wave<<5)+r;
        float acc = wave_reduce(dot4(*(const float4*)&Wy1[i*H_+k0], hA) + dot4(*(const float4*)&Wy1[i*H_+k0+4], hB));
        if (lane == 0) s_y[i] = acc + b_y[H_+i];
    }
    __syncthreads();
    const float4 yA = *(const float4*)&s_y[k0], yB = *(const float4*)&s_y[k0+4];
    if (wave < 8) {
#pragma unroll
        for (int r = 0; r < 4; ++r) {
            const int o = (wave<<2)+r;
            float acc = wave_reduce(dot4(*(const float4*)&Wf[o*H_+k0], yA) + dot4(*(const float4*)&Wf[o*H_+k0+4], yB));
            if (lane == 0) out[b*O_+o] = acc + bf[o];
        }
    }
}

extern "C" void kernel_launch(void* const* d_in, const int* in_sizes, int n_in,
                              void* d_out, int out_size, void* d_ws, size_t ws_size,
                              hipStream_t stream) {
    const int*   x    = (const int*)d_in[0];
    const int*   sl   = (const int*)d_in[1];
    const float* emb  = (const float*)d_in[2];
    const float* Whx  = (const float*)d_in[3];
    const float* Whh  = (const float*)d_in[4];
    const float* b_h  = (const float*)d_in[5];
    const float* Wyh  = (const float*)d_in[6];
    const float* b_y  = (const float*)d_in[7];
    const float* Wf   = (const float*)d_in[8];
    const float* bf   = (const float*)d_in[9];
    float* out = (float*)d_out;

    if (ws_size < WS_REQUIRED) {
        rnn_fused_fb<<<B_, 1024, 0, stream>>>(x, sl, emb, Whx, Whh, b_h, Wyh, b_y, Wf, bf, out);
        return;
    }

    float* ws_f = (float*)d_ws;
    float* h0_ring = ws_f + H0_OFF;
    float* h1_ring = ws_f + H1_OFF;
    float* h1f     = ws_f + HF_OFF;
    unsigned* flags = (unsigned*)(ws_f + FLAG_OFF);

    hipMemsetAsync(flags, 0, FLAG_UINTS * sizeof(unsigned), stream);
    rnn_pipe2<<<256, 512, 0, stream>>>(x, sl, emb, Whx, Whh, b_h,
                                       h0_ring, h1_ring, h1f, flags);
    head_kernel<<<B_, 512, 0, stream>>>(h1f, Wyh, b_y, Wf, bf, out);
}